// Round 6
// baseline (141.763 us; speedup 1.0000x reference)
//
#include <hip/hip_runtime.h>
#include <stdint.h>

typedef unsigned long long u64;
typedef unsigned int u32;

#define N_ANCH     36864
#define PRE_NMS_N  6000
#define POST_NMS_N 300
#define NBINS      8192     // value-uniform score bins
#define GK_CAP     8192     // grouped-key capacity (bins<=B total; ~6005 expected)
#define NWORDS     94       // ceil(6000/64)
#define S_WORDS    8        // staged words (candidates 0..511) in k_reduce
#define S_ROWS     512

// ---- workspace layout (bytes) ----
#define OFF_BBOX   0                       // float4 bbox[36864]   589824
#define OFF_KEYS   589824                  // u64 keys[36864]      294912
#define OFF_GK     884736                  // u64 gkeys[8192]       65536
#define OFF_SBOX   950272                  // float4 sboxes[6000]   96000
#define OFF_META   1046272                 // u32 meta[8]              32
#define OFF_CNT    1046304                 // u32 cnt[8192]         32768
#define OFF_OFFS   1079072                 // u32 offs[8193]        32776
#define OFF_IREM   1111848                 // u64 irem[94]            752
#define OFF_M      1112600                 // u64 M[6000*94]      4512000
#define WS_FULL    (OFF_M + (size_t)PRE_NMS_N * NWORDS * 8)

// Value-uniform monotone bin: higher score -> lower bin. Uniform scores spread
// evenly (~4.5 keys/bin); float-bit prefixes would collapse [0.5,1) into 16 bins.
__device__ __forceinline__ u32 score_bin(float s) {
    float v = fminf(fmaxf(s, 0.0f), 1.0f);
    u32 q = (u32)(v * 8192.0f);
    if (q > 8191u) q = 8191u;
    return 8191u - q;
}

// key = bin(16) | sortable_score(32) | idx(16); ascending u64 order
// == (score desc, idx asc) exactly (bin is monotone in score).
__device__ __forceinline__ u64 make_key(float s, u32 bin, u32 idx) {
    u32 u = __float_as_uint(s);
    u32 sortable = u ^ ((u >> 31) ? 0xFFFFFFFFu : 0x80000000u);
    u32 hi = ~sortable;                 // ascending == descending score
    return ((u64)bin << 48) | ((u64)hi << 16) | (u64)idx;
}

__device__ __forceinline__ u64 readlane_u64(u64 v, int l) {
    u32 lo = __builtin_amdgcn_readlane((u32)(v & 0xFFFFFFFFull), l);
    u32 hi = __builtin_amdgcn_readlane((u32)(v >> 32), l);
    return ((u64)hi << 32) | (u64)lo;
}

// K1: decode + clip + valid + key build
__global__ void k_decode(const float4* __restrict__ anchors,
                         const float* __restrict__ cls,
                         const float4* __restrict__ reg,
                         const int* __restrict__ img_w,
                         const int* __restrict__ img_h,
                         float4* __restrict__ bbox,
                         u64* __restrict__ keys) {
    int i = blockIdx.x * blockDim.x + threadIdx.x;
    if (i >= N_ANCH) return;

    float4 a = anchors[i];
    float4 r = reg[i];
    float w  = a.z - a.x, h = a.w - a.y;
    float cx = a.x + 0.5f * w, cy = a.y + 0.5f * h;
    float pcx = r.x * w + cx, pcy = r.y * h + cy;
    float pw = expf(r.z) * w,  ph = expf(r.w) * h;
    float b0 = pcx - 0.5f * pw, b1 = pcy - 0.5f * ph;
    float b2 = pcx + 0.5f * pw, b3 = pcy + 0.5f * ph;

    float fh = (float)img_h[0], fw = (float)img_w[0];
    // reference: cols 0,2 clipped to [0, img_h]; cols 1,3 to [0, img_w]
    b0 = fminf(fmaxf(b0, 0.0f), fh);
    b2 = fminf(fmaxf(b2, 0.0f), fh);
    b1 = fminf(fmaxf(b1, 0.0f), fw);
    b3 = fminf(fmaxf(b3, 0.0f), fw);

    bool valid = (b2 - b0 >= 16.0f) && (b3 - b1 >= 16.0f);
    float score = valid ? cls[i] : -1e9f;

    bbox[i] = make_float4(b0, b1, b2, b3);
    keys[i] = make_key(score, score_bin(score), (u32)i);
}

// K2: build 8192-bin histogram in LDS from keys, prefix-sum -> offsets, find
// boundary bin B (count(bin<B) < 6000 <= count(bin<=B)); zero cnt; init irem.
__global__ __launch_bounds__(1024) void k_scan(const u64* __restrict__ keys,
                                               u32* __restrict__ offs,
                                               u32* __restrict__ cnt,
                                               u64* __restrict__ irem,
                                               u32* __restrict__ meta) {
    __shared__ u32 hist[NBINS];   // 32 KiB
    __shared__ u32 psum[1024];
    int tid = threadIdx.x;
    for (int b = tid; b < NBINS; b += 1024) { hist[b] = 0u; cnt[b] = 0u; }
    if (tid < NWORDS) irem[tid] = ~0ull;
    __syncthreads();
    for (int i = tid; i < N_ANCH; i += 1024)
        atomicAdd(&hist[(u32)(keys[i] >> 48)], 1u);
    __syncthreads();

    u32 loc[8]; u32 s = 0;
    int base = tid * 8;
#pragma unroll
    for (int t = 0; t < 8; ++t) { loc[t] = hist[base + t]; s += loc[t]; }
    psum[tid] = s;
    __syncthreads();
    for (int off = 1; off < 1024; off <<= 1) {
        u32 v = (tid >= off) ? psum[tid - off] : 0u;
        __syncthreads();
        psum[tid] += v;
        __syncthreads();
    }
    u32 incl = psum[tid];
    u32 excl = incl - s;

    u32 run = excl;
#pragma unroll
    for (int t = 0; t < 8; ++t) { offs[base + t] = run; run += loc[t]; }
    if (tid == 1023) offs[NBINS] = incl;

    if (excl < (u32)PRE_NMS_N && incl >= (u32)PRE_NMS_N) {
        u32 c = excl;
#pragma unroll
        for (int t = 0; t < 8; ++t) {
            if (c + loc[t] >= (u32)PRE_NMS_N) {
                meta[1] = (u32)(base + t);   // boundary bin B
                meta[3] = c + loc[t];        // M = total keys in bins <= B
                break;
            }
            c += loc[t];
        }
    }
}

// K3: group keys of bins <= B into contiguous per-bin segments
__global__ void k_scatter(const u64* __restrict__ keys,
                          const u32* __restrict__ offs,
                          u32* __restrict__ cnt,
                          u64* __restrict__ gkeys,
                          const u32* __restrict__ meta) {
    int i = blockIdx.x * blockDim.x + threadIdx.x;
    if (i >= N_ANCH) return;
    u32 B = meta[1];
    u64 k = keys[i];
    u32 bin = (u32)(k >> 48);
    if (bin <= B) {
        u32 p = offs[bin] + atomicAdd(&cnt[bin], 1u);
        if (p < GK_CAP) gkeys[p] = k;
    }
}

// K4: exact rank = bin offset + #(smaller keys in own bin segment); scatter
// top-6000 boxes into sboxes[rank]; clear irem bit for valid boxes.
__global__ void k_rank(const u64* __restrict__ gkeys,
                       const u32* __restrict__ offs,
                       const float4* __restrict__ bbox,
                       float4* __restrict__ sboxes,
                       u64* __restrict__ irem,
                       const u32* __restrict__ meta) {
    int s = blockIdx.x * blockDim.x + threadIdx.x;
    u32 M = meta[3];
    if (M > GK_CAP) M = GK_CAP;
    if (s >= (int)M) return;
    u64 k = gkeys[s];
    u32 bin = (u32)(k >> 48);
    u32 st = offs[bin], en = offs[bin + 1];
    if (en > GK_CAP) en = GK_CAP;
    u32 r = st;
    for (u32 t = st; t < en; ++t) r += (gkeys[t] < k) ? 1u : 0u;
    if (r < (u32)PRE_NMS_N) {
        u32 idx = (u32)(k & 0xFFFFu);
        float4 b = bbox[idx];
        sboxes[r] = b;
        bool valid = (b.z - b.x >= 16.0f) && (b.w - b.y >= 16.0f);
        if (valid) atomicAnd(&irem[r >> 6], ~(1ull << (r & 63)));
    }
}

// K5a: suppression bitmask matrix, TRIANGULAR: row i only writes words >= i>>6.
// Words < i>>6 stay garbage (0xAA poison) -> k_reduce provably never reads them.
__global__ __launch_bounds__(1024) void k_iou(const float4* __restrict__ sboxes,
                                              u64* __restrict__ M) {
    __shared__ float4 sb[PRE_NMS_N];   // 96000 B
    int tid = threadIdx.x, lane = tid & 63, wave = tid >> 6;
    for (int r = tid; r < PRE_NMS_N; r += 1024) sb[r] = sboxes[r];
    __syncthreads();

    int i = blockIdx.x * 16 + wave;    // grid = 375 -> i in [0,6000)
    float4 bi = sb[i];
    float ai = (bi.z - bi.x) * (bi.w - bi.y);
    int w0 = i >> 6;
    u64* row = M + (size_t)i * NWORDS;
    for (int w = w0; w < NWORDS; ++w) {
        int j = (w << 6) + lane;
        bool sup = false;
        if (j > i && j < PRE_NMS_N) {
            float4 bj = sb[j];
            float aj = (bj.z - bj.x) * (bj.w - bj.y);
            float xx1 = fmaxf(bi.x, bj.x), yy1 = fmaxf(bi.y, bj.y);
            float xx2 = fminf(bi.z, bj.z), yy2 = fminf(bi.w, bj.w);
            float inter = fmaxf(xx2 - xx1, 0.0f) * fmaxf(yy2 - yy1, 0.0f);
            float iou = inter / (ai + aj - inter + 1e-9f);  // EXACT ref arithmetic
            sup = iou > 0.7f;
        }
        u64 m = __ballot(sup);
        if (lane == 0) row[w] = m;
    }
}

// K5b: serial greedy reduce, scratch-free. Word-at-a-time scan:
//  - S[w][q] (LDS, word-major) holds words 0..7 x rows 0..511 of M: covers the
//    expected exit (~320 candidates for 300 keeps at ~6% suppression).
//  - per word: vrow (one ds_read) gives lane l the diagonal word of row 64w+l;
//    serial chain is ffsll + readlane only (~20 cy per kept).
//  - future-word state recomputed at word transitions from <=300 kept indices
//    held in 5 named per-lane regs (no runtime-indexed arrays -> no scratch).
//  - words 8..93: same algorithm with global gathers (general fallback).
__global__ __launch_bounds__(256) void k_reduce(const float4* __restrict__ sboxes,
                                                const u64* __restrict__ M,
                                                const u64* __restrict__ irem,
                                                float* __restrict__ out) {
    __shared__ u64 S[S_WORDS * S_ROWS];   // 32 KiB
    __shared__ int kept[POST_NMS_N];
    int tid = threadIdx.x;

    // stage S (word-major) with all 4 waves; rows 0..511 words 0..7.
    for (int idx = tid; idx < S_WORDS * S_ROWS; idx += 256) {
        int q = idx >> 3, w = idx & 7;           // 8 consecutive tids = one row
        S[w * S_ROWS + q] = M[(size_t)q * NWORDS + w];
    }
    __syncthreads();
    if (tid >= 64) return;                        // wave 0 continues alone
    int lane = tid;

    u64 riem0 = irem[lane];                                     // word lane
    u64 riem1 = (lane < NWORDS - 64) ? irem[64 + lane] : ~0ull; // word 64+lane

    int kc = 0;
    u32 mk0 = 0, mk1 = 0, mk2 = 0, mk3 = 0, mk4 = 0;  // kept #(s*64+lane)

    for (int w = 0; w < NWORDS; ++w) {
        // ---- transition: cur = irem[w] | OR over kept rows' word w ----
        u64 add = 0;
        if (w < S_WORDS) {
            if (lane < kc)       add |= S[w * S_ROWS + mk0];
            if (64 + lane < kc)  add |= S[w * S_ROWS + mk1];
            if (128 + lane < kc) add |= S[w * S_ROWS + mk2];
            if (192 + lane < kc) add |= S[w * S_ROWS + mk3];
            if (256 + lane < kc) add |= S[w * S_ROWS + mk4];
        } else {
            if (lane < kc)       add |= M[(size_t)mk0 * NWORDS + w];
            if (64 + lane < kc)  add |= M[(size_t)mk1 * NWORDS + w];
            if (128 + lane < kc) add |= M[(size_t)mk2 * NWORDS + w];
            if (192 + lane < kc) add |= M[(size_t)mk3 * NWORDS + w];
            if (256 + lane < kc) add |= M[(size_t)mk4 * NWORDS + w];
        }
#pragma unroll
        for (int off = 32; off >= 1; off >>= 1)
            add |= __shfl_xor(add, off, 64);
        u64 iw = (w < 64) ? readlane_u64(riem0, w) : readlane_u64(riem1, w - 64);
        u64 cur = iw | add;

        // ---- vrow: lane l holds diagonal word of row 64w+l ----
        int q0 = w << 6;
        u64 vrow;
        if (w < S_WORDS) {
            vrow = S[w * S_ROWS + q0 + lane];
        } else {
            int qq = q0 + lane;
            if (qq > PRE_NMS_N - 1) qq = PRE_NMS_N - 1;  // addr clamp; bits masked by irem
            vrow = M[(size_t)qq * NWORDS + w];
        }

        // ---- serial in-word scan ----
        u64 avail = ~cur;
        while (avail) {
            int b = __ffsll((unsigned long long)avail) - 1;
            int q = q0 + b;
            if (lane == 0) kept[kc] = q;
            int slot = kc >> 6;
            if ((kc & 63) == lane) {
                if (slot == 0) mk0 = (u32)q;
                else if (slot == 1) mk1 = (u32)q;
                else if (slot == 2) mk2 = (u32)q;
                else if (slot == 3) mk3 = (u32)q;
                else mk4 = (u32)q;
            }
            u64 row = readlane_u64(vrow, b);   // suppressions by q within word w
            ++kc;
            if (kc >= POST_NMS_N) goto done_scan;
            avail &= ~row;
            avail &= ~(1ull << b);
        }
    }
done_scan:
    // lane0 wrote kept[]; single wave => in-order LDS visibility, no barrier
    for (int r = lane; r < POST_NMS_N; r += 64) {
        float4 v = make_float4(0.0f, 0.0f, 0.0f, 0.0f);
        if (r < kc) v = sboxes[kept[r]];
        ((float4*)out)[r] = v;
    }
}

// Fallback NMS (single fused kernel) if ws_size can't hold the bitmask matrix.
__global__ void k_nms(const float4* __restrict__ sboxes, float* __restrict__ out) {
    __shared__ float4 boxes[PRE_NMS_N];
    __shared__ u64 removed[NWORDS];
    __shared__ int kept[POST_NMS_N];
    int tid = threadIdx.x;
    int lane = tid & 63, wave = tid >> 6;

    for (int r = tid; r < PRE_NMS_N; r += 1024) boxes[r] = sboxes[r];
    __syncthreads();
    for (int r = tid; r < NWORDS * 64; r += 1024) {
        bool rm = true;
        if (r < PRE_NMS_N) {
            float4 b = boxes[r];
            rm = !((b.z - b.x >= 16.0f) && (b.w - b.y >= 16.0f));
        }
        u64 m = __ballot(rm);
        if (lane == 0) removed[r >> 6] = m;
    }
    __syncthreads();

    int kc = 0;
    int i = 0;
    while (i < PRE_NMS_N) {
        int w = i >> 6;
        u64 wd = removed[w] | ((1ull << (i & 63)) - 1ull);
        while (wd == ~0ull) {
            ++w;
            if (w >= NWORDS) break;
            wd = removed[w];
        }
        if (w >= NWORDS) break;
        i = (w << 6) + (__ffsll((u64)(~wd)) - 1);
        if (i >= PRE_NMS_N) break;

        if (tid == 0) kept[kc] = i;
        ++kc;
        if (kc >= POST_NMS_N) break;

        float4 bi = boxes[i];
        float area_i = (bi.z - bi.x) * (bi.w - bi.y);
        for (int c = (i >> 6) + wave; c < NWORDS; c += 16) {
            int j = (c << 6) + lane;
            bool sup = false;
            if (j > i && j < PRE_NMS_N) {
                float4 bj = boxes[j];
                float area_j = (bj.z - bj.x) * (bj.w - bj.y);
                float xx1 = fmaxf(bi.x, bj.x), yy1 = fmaxf(bi.y, bj.y);
                float xx2 = fminf(bi.z, bj.z), yy2 = fminf(bi.w, bj.w);
                float iw = fmaxf(xx2 - xx1, 0.0f), ih = fmaxf(yy2 - yy1, 0.0f);
                float inter = iw * ih;
                float iou = inter / (area_i + area_j - inter + 1e-9f);
                sup = iou > 0.7f;
            }
            u64 m = __ballot(sup);
            if (lane == 0 && m) removed[c] |= m;
        }
        __syncthreads();
        ++i;
    }
    __syncthreads();

    for (int r = tid; r < POST_NMS_N; r += 1024) {
        float4 v = make_float4(0.0f, 0.0f, 0.0f, 0.0f);
        if (r < kc) v = boxes[kept[r]];
        ((float4*)out)[r] = v;
    }
}

extern "C" void kernel_launch(void* const* d_in, const int* in_sizes, int n_in,
                              void* d_out, int out_size, void* d_ws, size_t ws_size,
                              hipStream_t stream) {
    const float4* anchors = (const float4*)d_in[0];
    const float*  cls     = (const float*)d_in[1];
    const float4* reg     = (const float4*)d_in[2];
    const int*    img_w   = (const int*)d_in[3];
    const int*    img_h   = (const int*)d_in[4];

    char* ws = (char*)d_ws;
    float4* bbox   = (float4*)(ws + OFF_BBOX);
    u64*    keys   = (u64*)   (ws + OFF_KEYS);
    u64*    gkeys  = (u64*)   (ws + OFF_GK);
    float4* sboxes = (float4*)(ws + OFF_SBOX);
    u32*    meta   = (u32*)   (ws + OFF_META);
    u32*    cnt    = (u32*)   (ws + OFF_CNT);
    u32*    offs   = (u32*)   (ws + OFF_OFFS);
    u64*    irem   = (u64*)   (ws + OFF_IREM);
    u64*    M      = (u64*)   (ws + OFF_M);

    k_decode <<<dim3((N_ANCH + 255) / 256), dim3(256), 0, stream>>>(
        anchors, cls, reg, img_w, img_h, bbox, keys);
    k_scan   <<<dim3(1), dim3(1024), 0, stream>>>(keys, offs, cnt, irem, meta);
    k_scatter<<<dim3((N_ANCH + 255) / 256), dim3(256), 0, stream>>>(
        keys, offs, cnt, gkeys, meta);
    k_rank   <<<dim3(GK_CAP / 256), dim3(256), 0, stream>>>(
        gkeys, offs, bbox, sboxes, irem, meta);

    if (ws_size >= WS_FULL) {
        k_iou    <<<dim3(PRE_NMS_N / 16), dim3(1024), 0, stream>>>(sboxes, M);
        k_reduce <<<dim3(1), dim3(256), 0, stream>>>(sboxes, M, irem, (float*)d_out);
    } else {
        k_nms    <<<dim3(1), dim3(1024), 0, stream>>>(sboxes, (float*)d_out);
    }
}

// Round 7
// 80.837 us; speedup vs baseline: 1.7537x; 1.7537x over previous
//
#include <hip/hip_runtime.h>
#include <stdint.h>

typedef unsigned long long u64;
typedef unsigned int u32;

#define N_ANCH     36864
#define PRE_NMS_N  6000
#define POST_NMS_N 300
#define NBINS      8192     // value-uniform score bins
#define GK_CAP     8192     // grouped-key capacity (bins<=B total; ~6005 expected)
#define NWORDS     94       // ceil(6000/64)
#define S_WORDS    8        // staged words (candidates 0..511) in k_reduce
#define S_ROWS     512

// ---- workspace layout (bytes) ----
#define OFF_BBOX   0                       // float4 bbox[36864]   589824
#define OFF_KEYS   589824                  // u64 keys[36864]      294912
#define OFF_GK     884736                  // u64 gkeys[8192]       65536
#define OFF_SBOX   950272                  // float4 sboxes[6000]   96000
#define OFF_META   1046272                 // u32 meta[8]              32
#define OFF_CNT    1046304                 // u32 cnt[8192]         32768
#define OFF_OFFS   1079072                 // u32 offs[8193]        32776
#define OFF_IREM   1111848                 // u64 irem[94]            752
#define OFF_M      1112600                 // u64 M[6000*94]      4512000
#define WS_FULL    (OFF_M + (size_t)PRE_NMS_N * NWORDS * 8)

// Value-uniform monotone bin: higher score -> lower bin.
__device__ __forceinline__ u32 score_bin(float s) {
    float v = fminf(fmaxf(s, 0.0f), 1.0f);
    u32 q = (u32)(v * 8192.0f);
    if (q > 8191u) q = 8191u;
    return 8191u - q;
}

// key = bin(16) | sortable_score(32) | idx(16); ascending u64 order
// == (score desc, idx asc) exactly (bin is monotone in score).
__device__ __forceinline__ u64 make_key(float s, u32 bin, u32 idx) {
    u32 u = __float_as_uint(s);
    u32 sortable = u ^ ((u >> 31) ? 0xFFFFFFFFu : 0x80000000u);
    u32 hi = ~sortable;
    return ((u64)bin << 48) | ((u64)hi << 16) | (u64)idx;
}

__device__ __forceinline__ u64 readlane_u64(u64 v, int l) {
    u32 lo = __builtin_amdgcn_readlane((u32)(v & 0xFFFFFFFFull), l);
    u32 hi = __builtin_amdgcn_readlane((u32)(v >> 32), l);
    return ((u64)hi << 32) | (u64)lo;
}

// n-th (0-based) set bit of m; caller guarantees popcount(m) > n.
__device__ __forceinline__ int nth_set_bit(u64 m, int n) {
    int pos = 0;
    u32 c = __popc((u32)m);
    if ((u32)n >= c) { n -= c; pos = 32; m >>= 32; }
    u32 x = (u32)m;
    c = __popc(x & 0xFFFFu);
    if ((u32)n >= c) { n -= c; pos += 16; x >>= 16; }
    c = __popc(x & 0xFFu);
    if ((u32)n >= c) { n -= c; pos += 8; x >>= 8; }
    c = __popc(x & 0xFu);
    if ((u32)n >= c) { n -= c; pos += 4; x >>= 4; }
    c = __popc(x & 0x3u);
    if ((u32)n >= c) { n -= c; pos += 2; x >>= 2; }
    c = x & 1u;
    if ((u32)n >= c) { pos += 1; }
    return pos;
}

// K1: decode + clip + valid + key build
__global__ void k_decode(const float4* __restrict__ anchors,
                         const float* __restrict__ cls,
                         const float4* __restrict__ reg,
                         const int* __restrict__ img_w,
                         const int* __restrict__ img_h,
                         float4* __restrict__ bbox,
                         u64* __restrict__ keys) {
    int i = blockIdx.x * blockDim.x + threadIdx.x;
    if (i >= N_ANCH) return;

    float4 a = anchors[i];
    float4 r = reg[i];
    float w  = a.z - a.x, h = a.w - a.y;
    float cx = a.x + 0.5f * w, cy = a.y + 0.5f * h;
    float pcx = r.x * w + cx, pcy = r.y * h + cy;
    float pw = expf(r.z) * w,  ph = expf(r.w) * h;
    float b0 = pcx - 0.5f * pw, b1 = pcy - 0.5f * ph;
    float b2 = pcx + 0.5f * pw, b3 = pcy + 0.5f * ph;

    float fh = (float)img_h[0], fw = (float)img_w[0];
    // reference: cols 0,2 clipped to [0, img_h]; cols 1,3 to [0, img_w]
    b0 = fminf(fmaxf(b0, 0.0f), fh);
    b2 = fminf(fmaxf(b2, 0.0f), fh);
    b1 = fminf(fmaxf(b1, 0.0f), fw);
    b3 = fminf(fmaxf(b3, 0.0f), fw);

    bool valid = (b2 - b0 >= 16.0f) && (b3 - b1 >= 16.0f);
    float score = valid ? cls[i] : -1e9f;

    bbox[i] = make_float4(b0, b1, b2, b3);
    keys[i] = make_key(score, score_bin(score), (u32)i);
}

// K2: LDS histogram + prefix sum -> offsets; boundary bin B; zero cnt; init irem.
__global__ __launch_bounds__(1024) void k_scan(const u64* __restrict__ keys,
                                               u32* __restrict__ offs,
                                               u32* __restrict__ cnt,
                                               u64* __restrict__ irem,
                                               u32* __restrict__ meta) {
    __shared__ u32 hist[NBINS];   // 32 KiB
    __shared__ u32 psum[1024];
    int tid = threadIdx.x;
    for (int b = tid; b < NBINS; b += 1024) { hist[b] = 0u; cnt[b] = 0u; }
    if (tid < NWORDS) irem[tid] = ~0ull;
    __syncthreads();
    for (int i = tid; i < N_ANCH; i += 1024)
        atomicAdd(&hist[(u32)(keys[i] >> 48)], 1u);
    __syncthreads();

    u32 loc[8]; u32 s = 0;
    int base = tid * 8;
#pragma unroll
    for (int t = 0; t < 8; ++t) { loc[t] = hist[base + t]; s += loc[t]; }
    psum[tid] = s;
    __syncthreads();
    for (int off = 1; off < 1024; off <<= 1) {
        u32 v = (tid >= off) ? psum[tid - off] : 0u;
        __syncthreads();
        psum[tid] += v;
        __syncthreads();
    }
    u32 incl = psum[tid];
    u32 excl = incl - s;

    u32 run = excl;
#pragma unroll
    for (int t = 0; t < 8; ++t) { offs[base + t] = run; run += loc[t]; }
    if (tid == 1023) offs[NBINS] = incl;

    if (excl < (u32)PRE_NMS_N && incl >= (u32)PRE_NMS_N) {
        u32 c = excl;
#pragma unroll
        for (int t = 0; t < 8; ++t) {
            if (c + loc[t] >= (u32)PRE_NMS_N) {
                meta[1] = (u32)(base + t);   // boundary bin B
                meta[3] = c + loc[t];        // M = total keys in bins <= B
                break;
            }
            c += loc[t];
        }
    }
}

// K3: group keys of bins <= B into contiguous per-bin segments
__global__ void k_scatter(const u64* __restrict__ keys,
                          const u32* __restrict__ offs,
                          u32* __restrict__ cnt,
                          u64* __restrict__ gkeys,
                          const u32* __restrict__ meta) {
    int i = blockIdx.x * blockDim.x + threadIdx.x;
    if (i >= N_ANCH) return;
    u32 B = meta[1];
    u64 k = keys[i];
    u32 bin = (u32)(k >> 48);
    if (bin <= B) {
        u32 p = offs[bin] + atomicAdd(&cnt[bin], 1u);
        if (p < GK_CAP) gkeys[p] = k;
    }
}

// K4: exact rank; scatter top-6000 boxes into sboxes[rank]; clear irem bit.
__global__ void k_rank(const u64* __restrict__ gkeys,
                       const u32* __restrict__ offs,
                       const float4* __restrict__ bbox,
                       float4* __restrict__ sboxes,
                       u64* __restrict__ irem,
                       const u32* __restrict__ meta) {
    int s = blockIdx.x * blockDim.x + threadIdx.x;
    u32 M = meta[3];
    if (M > GK_CAP) M = GK_CAP;
    if (s >= (int)M) return;
    u64 k = gkeys[s];
    u32 bin = (u32)(k >> 48);
    u32 st = offs[bin], en = offs[bin + 1];
    if (en > GK_CAP) en = GK_CAP;
    u32 r = st;
    for (u32 t = st; t < en; ++t) r += (gkeys[t] < k) ? 1u : 0u;
    if (r < (u32)PRE_NMS_N) {
        u32 idx = (u32)(k & 0xFFFFu);
        float4 b = bbox[idx];
        sboxes[r] = b;
        bool valid = (b.z - b.x >= 16.0f) && (b.w - b.y >= 16.0f);
        if (valid) atomicAnd(&irem[r >> 6], ~(1ull << (r & 63)));
    }
}

// K5a: suppression bitmask matrix, TRIANGULAR: row i writes only words >= i>>6.
__global__ __launch_bounds__(1024) void k_iou(const float4* __restrict__ sboxes,
                                              u64* __restrict__ M) {
    __shared__ float4 sb[PRE_NMS_N];   // 96000 B
    int tid = threadIdx.x, lane = tid & 63, wave = tid >> 6;
    for (int r = tid; r < PRE_NMS_N; r += 1024) sb[r] = sboxes[r];
    __syncthreads();

    int i = blockIdx.x * 16 + wave;    // grid = 375 -> i in [0,6000)
    float4 bi = sb[i];
    float ai = (bi.z - bi.x) * (bi.w - bi.y);
    int w0 = i >> 6;
    u64* row = M + (size_t)i * NWORDS;
    for (int w = w0; w < NWORDS; ++w) {
        int j = (w << 6) + lane;
        bool sup = false;
        if (j > i && j < PRE_NMS_N) {
            float4 bj = sb[j];
            float aj = (bj.z - bj.x) * (bj.w - bj.y);
            float xx1 = fmaxf(bi.x, bj.x), yy1 = fmaxf(bi.y, bj.y);
            float xx2 = fminf(bi.z, bj.z), yy2 = fminf(bi.w, bj.w);
            float inter = fmaxf(xx2 - xx1, 0.0f) * fmaxf(yy2 - yy1, 0.0f);
            float iou = inter / (ai + aj - inter + 1e-9f);  // EXACT ref arithmetic
            sup = iou > 0.7f;
        }
        u64 m = __ballot(sup);
        if (lane == 0) row[w] = m;
    }
}

// K5b: wholesale-word greedy reduce. Serial work scales with the number of
// SUPPRESSION-ACTIVE bits (~6% of candidates), not with candidates:
//  - per 64-candidate word: lane l holds inrow_l = M[q0+l][w] & avail (the
//    in-word suppressions). src = ballot(inrow!=0 & in-avail); tgt =
//    butterfly-OR(inrow). Passive bits (not in src|tgt) are kept wholesale.
//  - serial loop over active bits only (exact greedy: passive bits suppress
//    nobody in-word and are never suppressed in-word).
//  - kept set recorded as uniform kmask[w] bitmask; output reconstructed in
//    parallel at the end via prefix base + nth_set_bit select.
//  - words 0..7 x rows 0..511 staged in LDS; words >= 8 use global gathers
//    (general-input fallback; not taken for ~94% keep-rate data).
__global__ __launch_bounds__(256) void k_reduce(const float4* __restrict__ sboxes,
                                                const u64* __restrict__ M,
                                                const u64* __restrict__ irem,
                                                float* __restrict__ out) {
    __shared__ u64 S[S_WORDS * S_ROWS];   // 32 KiB, word-major: S[w*512+q]
    __shared__ u64 kmaskLDS[NWORDS];
    __shared__ u32 kbaseLDS[NWORDS];
    int tid = threadIdx.x;

    // stage words 0..7 x rows 0..511 (8 consecutive tids load one row's 64B)
    for (int idx = tid; idx < S_WORDS * S_ROWS; idx += 256) {
        int q = idx >> 3, w = idx & 7;
        S[w * S_ROWS + q] = M[(size_t)q * NWORDS + w];
    }
    __syncthreads();
    if (tid >= 64) return;                 // wave 0 continues alone
    int lane = tid;
    u64 lanebit = 1ull << lane;

    u64 riem0 = irem[lane];                                     // word lane
    u64 riem1 = (lane < NWORDS - 64) ? irem[64 + lane] : ~0ull; // word 64+lane

    int kc = 0;
    int wend = 0;
    for (int w = 0; w < NWORDS && kc < POST_NMS_N; ++w) {
        int q0 = w << 6;

        // ---- transition: cur = irem[w] | OR over kept prior rows' word w ----
        u64 add = 0;
        for (int wp = 0; wp < w; ++wp) {
            u64 km = kmaskLDS[wp];          // uniform broadcast read
            if (km & lanebit) {
                add |= (w < S_WORDS) ? S[w * S_ROWS + (wp << 6) + lane]
                                     : M[(size_t)((wp << 6) + lane) * NWORDS + w];
            }
        }
        if (w) {
#pragma unroll
            for (int off = 32; off >= 1; off >>= 1) add |= __shfl_xor(add, off, 64);
        }
        u64 iw = (w < 64) ? readlane_u64(riem0, w) : readlane_u64(riem1, w - 64);
        u64 avail = ~(iw | add);

        // ---- diagonal word: lane l = row q0+l 's word w (in-word suppressions) ----
        u64 vrow;
        if (w < S_WORDS) {
            vrow = S[w * S_ROWS + q0 + lane];
        } else {
            int qq = q0 + lane;
            if (qq > PRE_NMS_N - 1) qq = PRE_NMS_N - 1;  // clamped lanes not in avail
            vrow = M[(size_t)qq * NWORDS + w];
        }
        bool in_avail = (avail >> lane) & 1ull;
        u64 myrow = in_avail ? (vrow & avail) : 0ull;

        // ---- active bits: sources | targets ----
        u64 src = __ballot(myrow != 0ull);
        u64 tor = myrow;
#pragma unroll
        for (int off = 32; off >= 1; off >>= 1) tor |= __shfl_xor(tor, off, 64);
        u64 active = (src | tor) & avail;

        // ---- serial resolution over active bits only (exact greedy) ----
        u64 rm = 0;
        while (active) {
            int b = __ffsll((unsigned long long)active) - 1;
            active &= active - 1;
            if (!((rm >> b) & 1ull)) rm |= readlane_u64(myrow, b);
        }
        u64 keptw = avail & ~rm;

        if (lane == 0) { kmaskLDS[w] = keptw; kbaseLDS[w] = (u32)kc; }
        kc += __popcll(keptw);
        wend = w + 1;
    }

    // ---- output: first min(kc,300) kept, zero-pad tail ----
    int nout = kc < POST_NMS_N ? kc : POST_NMS_N;
    for (int r = lane; r < POST_NMS_N; r += 64) {
        float4 v = make_float4(0.0f, 0.0f, 0.0f, 0.0f);
        if (r < nout) {
            int w = 0;
            while (w + 1 < wend && (int)kbaseLDS[w + 1] <= r) ++w;
            int n = r - (int)kbaseLDS[w];
            int idx = (w << 6) + nth_set_bit(kmaskLDS[w], n);
            v = sboxes[idx];
        }
        ((float4*)out)[r] = v;
    }
}

// Fallback NMS (single fused kernel) if ws_size can't hold the bitmask matrix.
__global__ void k_nms(const float4* __restrict__ sboxes, float* __restrict__ out) {
    __shared__ float4 boxes[PRE_NMS_N];
    __shared__ u64 removed[NWORDS];
    __shared__ int kept[POST_NMS_N];
    int tid = threadIdx.x;
    int lane = tid & 63, wave = tid >> 6;

    for (int r = tid; r < PRE_NMS_N; r += 1024) boxes[r] = sboxes[r];
    __syncthreads();
    for (int r = tid; r < NWORDS * 64; r += 1024) {
        bool rm = true;
        if (r < PRE_NMS_N) {
            float4 b = boxes[r];
            rm = !((b.z - b.x >= 16.0f) && (b.w - b.y >= 16.0f));
        }
        u64 m = __ballot(rm);
        if (lane == 0) removed[r >> 6] = m;
    }
    __syncthreads();

    int kc = 0;
    int i = 0;
    while (i < PRE_NMS_N) {
        int w = i >> 6;
        u64 wd = removed[w] | ((1ull << (i & 63)) - 1ull);
        while (wd == ~0ull) {
            ++w;
            if (w >= NWORDS) break;
            wd = removed[w];
        }
        if (w >= NWORDS) break;
        i = (w << 6) + (__ffsll((u64)(~wd)) - 1);
        if (i >= PRE_NMS_N) break;

        if (tid == 0) kept[kc] = i;
        ++kc;
        if (kc >= POST_NMS_N) break;

        float4 bi = boxes[i];
        float area_i = (bi.z - bi.x) * (bi.w - bi.y);
        for (int c = (i >> 6) + wave; c < NWORDS; c += 16) {
            int j = (c << 6) + lane;
            bool sup = false;
            if (j > i && j < PRE_NMS_N) {
                float4 bj = boxes[j];
                float area_j = (bj.z - bj.x) * (bj.w - bj.y);
                float xx1 = fmaxf(bi.x, bj.x), yy1 = fmaxf(bi.y, bj.y);
                float xx2 = fminf(bi.z, bj.z), yy2 = fminf(bi.w, bj.w);
                float iw = fmaxf(xx2 - xx1, 0.0f), ih = fmaxf(yy2 - yy1, 0.0f);
                float inter = iw * ih;
                float iou = inter / (area_i + area_j - inter + 1e-9f);
                sup = iou > 0.7f;
            }
            u64 m = __ballot(sup);
            if (lane == 0 && m) removed[c] |= m;
        }
        __syncthreads();
        ++i;
    }
    __syncthreads();

    for (int r = tid; r < POST_NMS_N; r += 1024) {
        float4 v = make_float4(0.0f, 0.0f, 0.0f, 0.0f);
        if (r < kc) v = boxes[kept[r]];
        ((float4*)out)[r] = v;
    }
}

extern "C" void kernel_launch(void* const* d_in, const int* in_sizes, int n_in,
                              void* d_out, int out_size, void* d_ws, size_t ws_size,
                              hipStream_t stream) {
    const float4* anchors = (const float4*)d_in[0];
    const float*  cls     = (const float*)d_in[1];
    const float4* reg     = (const float4*)d_in[2];
    const int*    img_w   = (const int*)d_in[3];
    const int*    img_h   = (const int*)d_in[4];

    char* ws = (char*)d_ws;
    float4* bbox   = (float4*)(ws + OFF_BBOX);
    u64*    keys   = (u64*)   (ws + OFF_KEYS);
    u64*    gkeys  = (u64*)   (ws + OFF_GK);
    float4* sboxes = (float4*)(ws + OFF_SBOX);
    u32*    meta   = (u32*)   (ws + OFF_META);
    u32*    cnt    = (u32*)   (ws + OFF_CNT);
    u32*    offs   = (u32*)   (ws + OFF_OFFS);
    u64*    irem   = (u64*)   (ws + OFF_IREM);
    u64*    M      = (u64*)   (ws + OFF_M);

    k_decode <<<dim3((N_ANCH + 255) / 256), dim3(256), 0, stream>>>(
        anchors, cls, reg, img_w, img_h, bbox, keys);
    k_scan   <<<dim3(1), dim3(1024), 0, stream>>>(keys, offs, cnt, irem, meta);
    k_scatter<<<dim3((N_ANCH + 255) / 256), dim3(256), 0, stream>>>(
        keys, offs, cnt, gkeys, meta);
    k_rank   <<<dim3(GK_CAP / 256), dim3(256), 0, stream>>>(
        gkeys, offs, bbox, sboxes, irem, meta);

    if (ws_size >= WS_FULL) {
        k_iou    <<<dim3(PRE_NMS_N / 16), dim3(1024), 0, stream>>>(sboxes, M);
        k_reduce <<<dim3(1), dim3(256), 0, stream>>>(sboxes, M, irem, (float*)d_out);
    } else {
        k_nms    <<<dim3(1), dim3(1024), 0, stream>>>(sboxes, (float*)d_out);
    }
}

// Round 8
// 79.130 us; speedup vs baseline: 1.7915x; 1.0216x over previous
//
#include <hip/hip_runtime.h>
#include <stdint.h>

typedef unsigned long long u64;
typedef unsigned int u32;

#define N_ANCH     36864
#define PRE_NMS_N  6000
#define POST_NMS_N 300
#define NBINS      8192     // value-uniform score bins
#define GK_CAP     8192     // grouped-key LDS capacity (~6005 expected)
#define NWORDS     94       // ceil(6000/64)
#define S_WORDS    8        // staged words (candidates 0..511) in reduce
#define S_ROWS     512
#define GRID_A     36       // 36 x 1024 == N_ANCH exactly
#define GRID_B     250
#define ROWS_PB    24       // 250 * 24 == 6000

// ---- workspace layout (bytes) ----
#define OFF_BBOX   0                       // float4 bbox[36864]   589824
#define OFF_KEYS   589824                  // u64 keys[36864]      294912
#define OFF_SBOX   884736                  // float4 sboxes[6000]   96000
#define OFF_IREM   980736                  // u64 irem[94]            752
#define OFF_CTR    981488                  // u64 ctr[2]               16
#define OFF_M      981504                  // u64 M[6000*94]      4512000
#define WS_FULL    (OFF_M + (size_t)PRE_NMS_N * NWORDS * 8)

// Value-uniform monotone bin: higher score -> lower bin.
__device__ __forceinline__ u32 score_bin(float s) {
    float v = fminf(fmaxf(s, 0.0f), 1.0f);
    u32 q = (u32)(v * 8192.0f);
    if (q > 8191u) q = 8191u;
    return 8191u - q;
}

// key = bin(16) | sortable_score(32) | idx(16); ascending u64 order
// == (score desc, idx asc) exactly (bin is monotone in score).
__device__ __forceinline__ u64 make_key(float s, u32 bin, u32 idx) {
    u32 u = __float_as_uint(s);
    u32 sortable = u ^ ((u >> 31) ? 0xFFFFFFFFu : 0x80000000u);
    u32 hi = ~sortable;
    return ((u64)bin << 48) | ((u64)hi << 16) | (u64)idx;
}

__device__ __forceinline__ u64 readlane_u64(u64 v, int l) {
    u32 lo = __builtin_amdgcn_readlane((u32)(v & 0xFFFFFFFFull), l);
    u32 hi = __builtin_amdgcn_readlane((u32)(v >> 32), l);
    return ((u64)hi << 32) | (u64)lo;
}

// n-th (0-based) set bit of m; caller guarantees popcount(m) > n.
__device__ __forceinline__ int nth_set_bit(u64 m, int n) {
    int pos = 0;
    u32 c = __popc((u32)m);
    if ((u32)n >= c) { n -= c; pos = 32; m >>= 32; }
    u32 x = (u32)m;
    c = __popc(x & 0xFFFFu);
    if ((u32)n >= c) { n -= c; pos += 16; x >>= 16; }
    c = __popc(x & 0xFFu);
    if ((u32)n >= c) { n -= c; pos += 8; x >>= 8; }
    c = __popc(x & 0xFu);
    if ((u32)n >= c) { n -= c; pos += 4; x >>= 4; }
    c = __popc(x & 0x3u);
    if ((u32)n >= c) { n -= c; pos += 2; x >>= 2; }
    c = x & 1u;
    if ((u32)n >= c) { pos += 1; }
    return pos;
}

// ============ K_FRONT: decode (all blocks) + last-block selection chain ======
// Last-arriving block does histogram -> scan -> scatter -> rank entirely in
// LDS and emits sboxes (score-sorted top-6000 boxes) + irem (init removed
// mask). Arrival counter is a monotone u64: trigger iff old % GRID_A ==
// GRID_A-1 -- needs no reset, exact under 0xAA poison and graph replay.
__global__ __launch_bounds__(1024) void k_front(const float4* __restrict__ anchors,
                                                const float* __restrict__ cls,
                                                const float4* __restrict__ reg,
                                                const int* __restrict__ img_w,
                                                const int* __restrict__ img_h,
                                                float4* __restrict__ bbox,
                                                u64* __restrict__ keys,
                                                float4* __restrict__ sboxes,
                                                u64* __restrict__ irem,
                                                u64* __restrict__ ctr) {
    __shared__ u32 histoffs[NBINS + 1];   // hist, then overwritten by offsets
    __shared__ u32 psum[1024];
    __shared__ u32 cnt[NBINS];
    __shared__ u64 gk[GK_CAP];
    __shared__ u64 iremL[NWORDS];
    __shared__ u32 mB, mM, lastflag;

    int tid = threadIdx.x;
    int gi = blockIdx.x * 1024 + tid;     // exact: 36*1024 == N_ANCH

    // ---- decode + clip + valid + key (EXACT reference arithmetic) ----
    {
        float4 a = anchors[gi];
        float4 r = reg[gi];
        float w  = a.z - a.x, h = a.w - a.y;
        float cx = a.x + 0.5f * w, cy = a.y + 0.5f * h;
        float pcx = r.x * w + cx, pcy = r.y * h + cy;
        float pw = expf(r.z) * w,  ph = expf(r.w) * h;
        float b0 = pcx - 0.5f * pw, b1 = pcy - 0.5f * ph;
        float b2 = pcx + 0.5f * pw, b3 = pcy + 0.5f * ph;

        float fh = (float)img_h[0], fw = (float)img_w[0];
        // reference: cols 0,2 clipped to [0, img_h]; cols 1,3 to [0, img_w]
        b0 = fminf(fmaxf(b0, 0.0f), fh);
        b2 = fminf(fmaxf(b2, 0.0f), fh);
        b1 = fminf(fmaxf(b1, 0.0f), fw);
        b3 = fminf(fmaxf(b3, 0.0f), fw);

        bool valid = (b2 - b0 >= 16.0f) && (b3 - b1 >= 16.0f);
        float score = valid ? cls[gi] : -1e9f;

        bbox[gi] = make_float4(b0, b1, b2, b3);
        keys[gi] = make_key(score, score_bin(score), (u32)gi);
    }

    // ---- arrival: last block proceeds ----
    __syncthreads();
    if (tid == 0) {
        __threadfence();
        u64 old = atomicAdd(ctr, 1ull);
        lastflag = ((old % (u64)GRID_A) == (u64)(GRID_A - 1)) ? 1u : 0u;
    }
    __syncthreads();
    if (!lastflag) return;
    __threadfence();   // acquire: see all blocks' bbox/keys

    // ---- histogram (LDS) ----
    for (int b = tid; b < NBINS; b += 1024) histoffs[b] = 0u;
    if (tid < NWORDS) iremL[tid] = ~0ull;
    __syncthreads();
    for (int i = tid; i < N_ANCH; i += 1024)
        atomicAdd(&histoffs[(u32)(keys[i] >> 48)], 1u);
    __syncthreads();

    // ---- scan -> offsets (overwrite histoffs); find boundary bin ----
    u32 loc[8]; u32 s = 0;
    int base = tid * 8;
#pragma unroll
    for (int t = 0; t < 8; ++t) { loc[t] = histoffs[base + t]; s += loc[t]; }
    psum[tid] = s;
    __syncthreads();
    for (int off = 1; off < 1024; off <<= 1) {
        u32 v = (tid >= off) ? psum[tid - off] : 0u;
        __syncthreads();
        psum[tid] += v;
        __syncthreads();
    }
    u32 incl = psum[tid];
    u32 excl = incl - s;
    u32 run = excl;
#pragma unroll
    for (int t = 0; t < 8; ++t) { histoffs[base + t] = run; run += loc[t]; }
    if (tid == 1023) histoffs[NBINS] = incl;
    if (excl < (u32)PRE_NMS_N && incl >= (u32)PRE_NMS_N) {
        u32 c = excl;
#pragma unroll
        for (int t = 0; t < 8; ++t) {
            if (c + loc[t] >= (u32)PRE_NMS_N) { mB = (u32)(base + t); mM = c + loc[t]; break; }
            c += loc[t];
        }
    }
    for (int b = tid; b < NBINS; b += 1024) cnt[b] = 0u;
    __syncthreads();

    // ---- scatter keys of bins <= B into per-bin LDS segments ----
    u32 B = mB;
    for (int i = tid; i < N_ANCH; i += 1024) {
        u64 k = keys[i];
        u32 bin = (u32)(k >> 48);
        if (bin <= B) {
            u32 p = histoffs[bin] + atomicAdd(&cnt[bin], 1u);
            if (p < GK_CAP) gk[p] = k;
        }
    }
    __syncthreads();

    // ---- rank + scatter boxes + irem bits ----
    u32 Mtot = mM > (u32)GK_CAP ? (u32)GK_CAP : mM;
    for (int s2 = tid; s2 < (int)Mtot; s2 += 1024) {
        u64 k = gk[s2];
        u32 bin = (u32)(k >> 48);
        u32 st = histoffs[bin], en = histoffs[bin + 1];
        if (en > (u32)GK_CAP) en = (u32)GK_CAP;
        u32 r = st;
        for (u32 t = st; t < en; ++t) r += (gk[t] < k) ? 1u : 0u;
        if (r < (u32)PRE_NMS_N) {
            u32 idx = (u32)(k & 0xFFFFu);
            float4 b = bbox[idx];
            sboxes[r] = b;
            bool valid = (b.z - b.x >= 16.0f) && (b.w - b.y >= 16.0f);
            if (valid) atomicAnd(&iremL[r >> 6], ~(1ull << (r & 63)));
        }
    }
    __syncthreads();
    if (tid < NWORDS) irem[tid] = iremL[tid];
}

// ============ K_BACK: IoU bitmask rows (all blocks) + last-block reduce ======
__global__ __launch_bounds__(1024) void k_back(const float4* __restrict__ sboxes,
                                               const u64* __restrict__ irem,
                                               u64* __restrict__ Mmat,
                                               u64* __restrict__ ctr,
                                               float* __restrict__ out) {
    __shared__ float4 sb[PRE_NMS_N];       // 96000 B
    __shared__ u64 S[S_WORDS * S_ROWS];    // 32768 B
    __shared__ u64 kmaskLDS[NWORDS];
    __shared__ u32 kbaseLDS[NWORDS];
    __shared__ u32 lastflag;

    int tid = threadIdx.x, lane = tid & 63, wave = tid >> 6;
    for (int r = tid; r < PRE_NMS_N; r += 1024) sb[r] = sboxes[r];
    __syncthreads();

    // ---- triangular M rows: block b owns rows {b + 250*t} ----
    for (int t = wave; t < ROWS_PB; t += 16) {
        int i = blockIdx.x + GRID_B * t;   // in [0,6000)
        float4 bi = sb[i];
        float ai = (bi.z - bi.x) * (bi.w - bi.y);
        int w0 = i >> 6;
        u64* row = Mmat + (size_t)i * NWORDS;
        for (int w = w0; w < NWORDS; ++w) {
            int j = (w << 6) + lane;
            bool sup = false;
            if (j > i && j < PRE_NMS_N) {
                float4 bj = sb[j];
                float aj = (bj.z - bj.x) * (bj.w - bj.y);
                float xx1 = fmaxf(bi.x, bj.x), yy1 = fmaxf(bi.y, bj.y);
                float xx2 = fminf(bi.z, bj.z), yy2 = fminf(bi.w, bj.w);
                float inter = fmaxf(xx2 - xx1, 0.0f) * fmaxf(yy2 - yy1, 0.0f);
                float iou = inter / (ai + aj - inter + 1e-9f);  // EXACT ref arithmetic
                sup = iou > 0.7f;
            }
            u64 m = __ballot(sup);
            if (lane == 0) row[w] = m;
        }
    }

    // ---- arrival: last block reduces ----
    __syncthreads();
    if (tid == 0) {
        __threadfence();
        u64 old = atomicAdd(ctr, 1ull);
        lastflag = ((old % (u64)GRID_B) == (u64)(GRID_B - 1)) ? 1u : 0u;
    }
    __syncthreads();
    if (!lastflag) return;
    __threadfence();   // acquire: see all blocks' M rows

    // stage words 0..7 x rows 0..511 (word-major)
    for (int idx = tid; idx < S_WORDS * S_ROWS; idx += 1024) {
        int q = idx >> 3, w = idx & 7;
        S[w * S_ROWS + q] = Mmat[(size_t)q * NWORDS + w];
    }
    __syncthreads();
    if (tid >= 64) return;                 // wave 0 continues alone
    u64 lanebit = 1ull << lane;

    u64 riem0 = irem[lane];
    u64 riem1 = (lane < NWORDS - 64) ? irem[64 + lane] : ~0ull;

    int kc = 0;
    int wend = 0;
    for (int w = 0; w < NWORDS && kc < POST_NMS_N; ++w) {
        int q0 = w << 6;

        // transition: cur = irem[w] | OR over kept prior rows' word w
        u64 add = 0;
        for (int wp = 0; wp < w; ++wp) {
            u64 km = kmaskLDS[wp];
            if (km & lanebit) {
                add |= (w < S_WORDS) ? S[w * S_ROWS + (wp << 6) + lane]
                                     : Mmat[(size_t)((wp << 6) + lane) * NWORDS + w];
            }
        }
        if (w) {
#pragma unroll
            for (int off = 32; off >= 1; off >>= 1) add |= __shfl_xor(add, off, 64);
        }
        u64 iw = (w < 64) ? readlane_u64(riem0, w) : readlane_u64(riem1, w - 64);
        u64 avail = ~(iw | add);

        // diagonal word: lane l = row q0+l's word w (in-word suppressions)
        u64 vrow;
        if (w < S_WORDS) {
            vrow = S[w * S_ROWS + q0 + lane];
        } else {
            int qq = q0 + lane;
            if (qq > PRE_NMS_N - 1) qq = PRE_NMS_N - 1;  // clamped lanes not in avail
            vrow = Mmat[(size_t)qq * NWORDS + w];
        }
        bool in_avail = (avail >> lane) & 1ull;
        u64 myrow = in_avail ? (vrow & avail) : 0ull;

        // active bits = sources | targets; passive bits kept wholesale
        u64 src = __ballot(myrow != 0ull);
        u64 tor = myrow;
#pragma unroll
        for (int off = 32; off >= 1; off >>= 1) tor |= __shfl_xor(tor, off, 64);
        u64 active = (src | tor) & avail;

        u64 rm = 0;
        while (active) {
            int b = __ffsll((unsigned long long)active) - 1;
            active &= active - 1;
            if (!((rm >> b) & 1ull)) rm |= readlane_u64(myrow, b);
        }
        u64 keptw = avail & ~rm;

        if (lane == 0) { kmaskLDS[w] = keptw; kbaseLDS[w] = (u32)kc; }
        kc += __popcll(keptw);
        wend = w + 1;
    }

    // output: first min(kc,300) kept, zero-pad tail
    int nout = kc < POST_NMS_N ? kc : POST_NMS_N;
    for (int r = lane; r < POST_NMS_N; r += 64) {
        float4 v = make_float4(0.0f, 0.0f, 0.0f, 0.0f);
        if (r < nout) {
            int w = 0;
            while (w + 1 < wend && (int)kbaseLDS[w + 1] <= r) ++w;
            int n = r - (int)kbaseLDS[w];
            int idx = (w << 6) + nth_set_bit(kmaskLDS[w], n);
            v = sb[idx];
        }
        ((float4*)out)[r] = v;
    }
}

// Fallback NMS (single fused kernel) if ws_size can't hold the bitmask matrix.
__global__ void k_nms(const float4* __restrict__ sboxes, float* __restrict__ out) {
    __shared__ float4 boxes[PRE_NMS_N];
    __shared__ u64 removed[NWORDS];
    __shared__ int kept[POST_NMS_N];
    int tid = threadIdx.x;
    int lane = tid & 63, wave = tid >> 6;

    for (int r = tid; r < PRE_NMS_N; r += 1024) boxes[r] = sboxes[r];
    __syncthreads();
    for (int r = tid; r < NWORDS * 64; r += 1024) {
        bool rm = true;
        if (r < PRE_NMS_N) {
            float4 b = boxes[r];
            rm = !((b.z - b.x >= 16.0f) && (b.w - b.y >= 16.0f));
        }
        u64 m = __ballot(rm);
        if (lane == 0) removed[r >> 6] = m;
    }
    __syncthreads();

    int kc = 0;
    int i = 0;
    while (i < PRE_NMS_N) {
        int w = i >> 6;
        u64 wd = removed[w] | ((1ull << (i & 63)) - 1ull);
        while (wd == ~0ull) {
            ++w;
            if (w >= NWORDS) break;
            wd = removed[w];
        }
        if (w >= NWORDS) break;
        i = (w << 6) + (__ffsll((u64)(~wd)) - 1);
        if (i >= PRE_NMS_N) break;

        if (tid == 0) kept[kc] = i;
        ++kc;
        if (kc >= POST_NMS_N) break;

        float4 bi = boxes[i];
        float area_i = (bi.z - bi.x) * (bi.w - bi.y);
        for (int c = (i >> 6) + wave; c < NWORDS; c += 16) {
            int j = (c << 6) + lane;
            bool sup = false;
            if (j > i && j < PRE_NMS_N) {
                float4 bj = boxes[j];
                float area_j = (bj.z - bj.x) * (bj.w - bj.y);
                float xx1 = fmaxf(bi.x, bj.x), yy1 = fmaxf(bi.y, bj.y);
                float xx2 = fminf(bi.z, bj.z), yy2 = fminf(bi.w, bj.w);
                float iw = fmaxf(xx2 - xx1, 0.0f), ih = fmaxf(yy2 - yy1, 0.0f);
                float inter = iw * ih;
                float iou = inter / (area_i + area_j - inter + 1e-9f);
                sup = iou > 0.7f;
            }
            u64 m = __ballot(sup);
            if (lane == 0 && m) removed[c] |= m;
        }
        __syncthreads();
        ++i;
    }
    __syncthreads();

    for (int r = tid; r < POST_NMS_N; r += 1024) {
        float4 v = make_float4(0.0f, 0.0f, 0.0f, 0.0f);
        if (r < kc) v = boxes[kept[r]];
        ((float4*)out)[r] = v;
    }
}

extern "C" void kernel_launch(void* const* d_in, const int* in_sizes, int n_in,
                              void* d_out, int out_size, void* d_ws, size_t ws_size,
                              hipStream_t stream) {
    const float4* anchors = (const float4*)d_in[0];
    const float*  cls     = (const float*)d_in[1];
    const float4* reg     = (const float4*)d_in[2];
    const int*    img_w   = (const int*)d_in[3];
    const int*    img_h   = (const int*)d_in[4];

    char* ws = (char*)d_ws;
    float4* bbox   = (float4*)(ws + OFF_BBOX);
    u64*    keys   = (u64*)   (ws + OFF_KEYS);
    float4* sboxes = (float4*)(ws + OFF_SBOX);
    u64*    irem   = (u64*)   (ws + OFF_IREM);
    u64*    ctr    = (u64*)   (ws + OFF_CTR);
    u64*    Mmat   = (u64*)   (ws + OFF_M);

    k_front<<<dim3(GRID_A), dim3(1024), 0, stream>>>(
        anchors, cls, reg, img_w, img_h, bbox, keys, sboxes, irem, ctr);

    if (ws_size >= WS_FULL) {
        k_back<<<dim3(GRID_B), dim3(1024), 0, stream>>>(
            sboxes, irem, Mmat, ctr + 1, (float*)d_out);
    } else {
        k_nms<<<dim3(1), dim3(1024), 0, stream>>>(sboxes, (float*)d_out);
    }
}

// Round 9
// 69.249 us; speedup vs baseline: 2.0472x; 1.1427x over previous
//
#include <hip/hip_runtime.h>
#include <stdint.h>

typedef unsigned long long u64;
typedef unsigned int u32;

#define N_ANCH     36864
#define PRE_NMS_N  6000
#define POST_NMS_N 300
#define NBINS_F    8192     // fallback full bin count
#define NBINS_H    2048     // happy-path scan width
#define PF_BIN     1536     // pre-filter: append keys with bin < 1536 (score >= 0.8125)
#define GKRAW_CAP  16384
#define GKH_CAP    8192
#define NWORDS     94       // ceil(6000/64)
#define S_WORDS    8        // staged words (candidates 0..511)
#define S_ROWS     512
#define GRID_A     36       // 36 x 1024 == N_ANCH
#define GRID_B     256      // rows {b, b+256} per block

// ---- workspace layout (bytes) ----
#define OFF_BBOX   0            // float4 bbox[36864]       589824
#define OFF_KEYS   589824       // u64 keys[36864]          294912 (fallback only)
#define OFF_SBOX   884736       // float4 sboxes[6000]       96000
#define OFF_IREM   980736       // u64 irem[94]                752
#define OFF_CTR    981488       // [0..3]=appendCtr u32, [8..15]=ctrA u64, [16..23]=ctrB u64
#define OFF_GKRAW  981552       // u64 gkraw[16384]         131072
#define OFF_M      1112624      // u64 M[512*8]              32768
#define WS_FULL    (OFF_M + (size_t)S_ROWS * S_WORDS * 8)

// Value-uniform monotone bin: higher score -> lower bin.
__device__ __forceinline__ u32 score_bin(float s) {
    float v = fminf(fmaxf(s, 0.0f), 1.0f);
    u32 q = (u32)(v * 8192.0f);
    if (q > 8191u) q = 8191u;
    return 8191u - q;
}

// key = bin(16) | sortable_score(32) | idx(16); ascending u64 ==
// (score desc, idx asc) exactly.
__device__ __forceinline__ u64 make_key(float s, u32 bin, u32 idx) {
    u32 u = __float_as_uint(s);
    u32 sortable = u ^ ((u >> 31) ? 0xFFFFFFFFu : 0x80000000u);
    u32 hi = ~sortable;
    return ((u64)bin << 48) | ((u64)hi << 16) | (u64)idx;
}

__device__ __forceinline__ u64 readlane_u64(u64 v, int l) {
    u32 lo = __builtin_amdgcn_readlane((u32)(v & 0xFFFFFFFFull), l);
    u32 hi = __builtin_amdgcn_readlane((u32)(v >> 32), l);
    return ((u64)hi << 32) | (u64)lo;
}

__device__ __forceinline__ int nth_set_bit(u64 m, int n) {
    int pos = 0;
    u32 c = __popc((u32)m);
    if ((u32)n >= c) { n -= c; pos = 32; m >>= 32; }
    u32 x = (u32)m;
    c = __popc(x & 0xFFFFu);
    if ((u32)n >= c) { n -= c; pos += 16; x >>= 16; }
    c = __popc(x & 0xFFu);
    if ((u32)n >= c) { n -= c; pos += 8; x >>= 8; }
    c = __popc(x & 0xFu);
    if ((u32)n >= c) { n -= c; pos += 4; x >>= 4; }
    c = __popc(x & 0x3u);
    if ((u32)n >= c) { n -= c; pos += 2; x >>= 2; }
    c = x & 1u;
    if ((u32)n >= c) { pos += 1; }
    return pos;
}

// EXACT reference IoU decision (identical expression tree to all prior rounds)
__device__ __forceinline__ bool iou_gt(float4 a, float4 b) {
    float aa = (a.z - a.x) * (a.w - a.y);
    float ab = (b.z - b.x) * (b.w - b.y);
    float xx1 = fmaxf(a.x, b.x), yy1 = fmaxf(a.y, b.y);
    float xx2 = fminf(a.z, b.z), yy2 = fminf(a.w, b.w);
    float inter = fmaxf(xx2 - xx1, 0.0f) * fmaxf(yy2 - yy1, 0.0f);
    float iou = inter / (aa + ab - inter + 1e-9f);
    return iou > 0.7f;
}

// ===== K_FRONT: decode + prefilter-append (all blocks); last block: selection =====
__global__ __launch_bounds__(1024) void k_front(const float4* __restrict__ anchors,
                                                const float* __restrict__ cls,
                                                const float4* __restrict__ reg,
                                                const int* __restrict__ img_w,
                                                const int* __restrict__ img_h,
                                                float4* __restrict__ bbox,
                                                u64* __restrict__ keys,
                                                u64* __restrict__ gkraw,
                                                float4* __restrict__ sboxes,
                                                u64* __restrict__ irem,
                                                u32* __restrict__ actr,
                                                u64* __restrict__ ctrA) {
    __shared__ u64 gkA[GKH_CAP];            // 64 KiB (fallback: hist8192+cnt8192 as u32)
    __shared__ u64 gkB[GKH_CAP];            // 64 KiB
    __shared__ u32 histoffs[NBINS_H + 1];   // happy-path hist -> offs
    __shared__ u32 cntH[NBINS_H];
    __shared__ u32 psum[1024];
    __shared__ u64 iremL[NWORDS];
    __shared__ u32 offs_top;
    __shared__ u32 mB, mM, lastflag, sCount;

    int tid = threadIdx.x, lane = tid & 63;
    int gi = blockIdx.x * 1024 + tid;       // exact: 36*1024 == N_ANCH

    // ---- decode + clip + valid + key (EXACT reference arithmetic) ----
    u32 bin;
    {
        float4 a = anchors[gi];
        float4 r = reg[gi];
        float w  = a.z - a.x, h = a.w - a.y;
        float cx = a.x + 0.5f * w, cy = a.y + 0.5f * h;
        float pcx = r.x * w + cx, pcy = r.y * h + cy;
        float pw = expf(r.z) * w,  ph = expf(r.w) * h;
        float b0 = pcx - 0.5f * pw, b1 = pcy - 0.5f * ph;
        float b2 = pcx + 0.5f * pw, b3 = pcy + 0.5f * ph;

        float fh = (float)img_h[0], fw = (float)img_w[0];
        b0 = fminf(fmaxf(b0, 0.0f), fh);
        b2 = fminf(fmaxf(b2, 0.0f), fh);
        b1 = fminf(fmaxf(b1, 0.0f), fw);
        b3 = fminf(fmaxf(b3, 0.0f), fw);

        bool valid = (b2 - b0 >= 16.0f) && (b3 - b1 >= 16.0f);
        float score = valid ? cls[gi] : -1e9f;

        bbox[gi] = make_float4(b0, b1, b2, b3);
        bin = score_bin(score);
        u64 key = make_key(score, bin, (u32)gi);
        keys[gi] = key;

        // ---- wave-aggregated append of high-score keys ----
        bool qf = bin < PF_BIN;
        u64 ball = __ballot(qf);
        u32 n = (u32)__popcll(ball);
        u32 base = 0;
        if (lane == 0 && n) base = atomicAdd(actr, n);
        base = (u32)__shfl((int)base, 0, 64);
        if (qf) {
            u32 pos = base + (u32)__popcll(ball & ((1ull << lane) - 1ull));
            if (pos < GKRAW_CAP) gkraw[pos] = key;
        }
    }

    // ---- arrival ----
    __syncthreads();
    if (tid == 0) {
        __threadfence();
        u64 old = atomicAdd(ctrA, 1ull);
        u32 lf = (old == (u64)(GRID_A - 1)) ? 1u : 0u;
        lastflag = lf;
        if (lf) { __threadfence(); sCount = atomicAdd(actr, 0u); }
    }
    __syncthreads();
    if (!lastflag) return;
    __threadfence();   // acquire: see all blocks' bbox/keys/gkraw

    if (tid < NWORDS) iremL[tid] = ~0ull;
    u32 count = sCount;
    bool happy = (count >= (u32)PRE_NMS_N) && (count <= (u32)GKH_CAP);

    if (happy) {
        // ---- selection over the appended set only (top-6000 subset proof:
        // every non-appended key has bin >= PF_BIN > any appended bin) ----
        for (int b = tid; b < NBINS_H; b += 1024) { histoffs[b] = 0u; cntH[b] = 0u; }
        __syncthreads();
        for (int i = tid; i < (int)count; i += 1024) {
            u64 k = gkraw[i];
            gkA[i] = k;
            atomicAdd(&histoffs[(u32)(k >> 48)], 1u);
        }
        __syncthreads();
        u32 l0 = histoffs[2 * tid], l1 = histoffs[2 * tid + 1];
        u32 s = l0 + l1;
        psum[tid] = s;
        __syncthreads();
        for (int off = 1; off < 1024; off <<= 1) {
            u32 v = (tid >= off) ? psum[tid - off] : 0u;
            __syncthreads();
            psum[tid] += v;
            __syncthreads();
        }
        u32 incl = psum[tid], excl = incl - s;
        histoffs[2 * tid] = excl;
        histoffs[2 * tid + 1] = excl + l0;
        if (tid == 1023) histoffs[NBINS_H] = incl;
        if (excl < (u32)PRE_NMS_N && incl >= (u32)PRE_NMS_N) {
            if (excl + l0 >= (u32)PRE_NMS_N) { mB = 2 * tid;     mM = excl + l0; }
            else                             { mB = 2 * tid + 1; mM = incl; }
        }
        __syncthreads();
        u32 B = mB, Mtot = mM;
        for (int i = tid; i < (int)count; i += 1024) {
            u64 k = gkA[i];
            u32 bn = (u32)(k >> 48);
            if (bn <= B) {
                u32 p = histoffs[bn] + atomicAdd(&cntH[bn], 1u);
                if (p < (u32)GKH_CAP) gkB[p] = k;
            }
        }
        __syncthreads();
        for (int i = tid; i < (int)Mtot; i += 1024) {
            u64 k = gkB[i];
            u32 bn = (u32)(k >> 48);
            u32 st = histoffs[bn], en = histoffs[bn + 1];
            u32 rr = st;
            for (u32 t = st; t < en; ++t) rr += (gkB[t] < k) ? 1u : 0u;
            if (rr < (u32)PRE_NMS_N) {
                u32 idx = (u32)(k & 0xFFFFu);
                sboxes[rr] = bbox[idx];
                // appended => bin<1536 => score>=0.8125 => valid
                atomicAnd(&iremL[rr >> 6], ~(1ull << (rr & 63)));
            }
        }
    } else {
        // ---- exact fallback: full 8192-bin path over all keys (R8-proven) ----
        u32* histF = (u32*)gkA;              // [0..8191]
        u32* cntF  = ((u32*)gkA) + NBINS_F;  // [8192..16383]
        for (int b = tid; b < NBINS_F; b += 1024) { histF[b] = 0u; cntF[b] = 0u; }
        __syncthreads();
        for (int i = tid; i < N_ANCH; i += 1024)
            atomicAdd(&histF[(u32)(keys[i] >> 48)], 1u);
        __syncthreads();
        u32 loc[8]; u32 s = 0;
        int base8 = tid * 8;
#pragma unroll
        for (int t = 0; t < 8; ++t) { loc[t] = histF[base8 + t]; s += loc[t]; }
        psum[tid] = s;
        __syncthreads();
        for (int off = 1; off < 1024; off <<= 1) {
            u32 v = (tid >= off) ? psum[tid - off] : 0u;
            __syncthreads();
            psum[tid] += v;
            __syncthreads();
        }
        u32 incl = psum[tid], excl = incl - s;
        u32 run = excl;
#pragma unroll
        for (int t = 0; t < 8; ++t) { histF[base8 + t] = run; run += loc[t]; }
        if (tid == 1023) offs_top = incl;
        if (excl < (u32)PRE_NMS_N && incl >= (u32)PRE_NMS_N) {
            u32 c = excl;
#pragma unroll
            for (int t = 0; t < 8; ++t) {
                if (c + loc[t] >= (u32)PRE_NMS_N) { mB = (u32)(base8 + t); mM = c + loc[t]; break; }
                c += loc[t];
            }
        }
        __syncthreads();
        u32 B = mB;
        for (int i = tid; i < N_ANCH; i += 1024) {
            u64 k = keys[i];
            u32 bn = (u32)(k >> 48);
            if (bn <= B) {
                u32 p = histF[bn] + atomicAdd(&cntF[bn], 1u);
                if (p < (u32)GKH_CAP) gkB[p] = k;
            }
        }
        __syncthreads();
        u32 Mtot = mM > (u32)GKH_CAP ? (u32)GKH_CAP : mM;
        for (int i = tid; i < (int)Mtot; i += 1024) {
            u64 k = gkB[i];
            u32 bn = (u32)(k >> 48);
            u32 st = histF[bn];
            u32 en = (bn + 1 < (u32)NBINS_F) ? histF[bn + 1] : offs_top;
            if (en > (u32)GKH_CAP) en = (u32)GKH_CAP;
            u32 rr = st;
            for (u32 t = st; t < en; ++t) rr += (gkB[t] < k) ? 1u : 0u;
            if (rr < (u32)PRE_NMS_N) {
                u32 idx = (u32)(k & 0xFFFFu);
                float4 b = bbox[idx];
                sboxes[rr] = b;
                bool valid = (b.z - b.x >= 16.0f) && (b.w - b.y >= 16.0f);
                if (valid) atomicAnd(&iremL[rr >> 6], ~(1ull << (rr & 63)));
            }
        }
    }
    __syncthreads();
    if (tid < NWORDS) irem[tid] = iremL[tid];
}

// ===== K_BACK: eager IoU over rows<512 x words<8 (all blocks); last block reduces =====
__global__ __launch_bounds__(64) void k_back(const float4* __restrict__ sboxes,
                                             const u64* __restrict__ irem,
                                             u64* __restrict__ Mmat,
                                             u64* __restrict__ ctrB,
                                             float* __restrict__ out) {
    __shared__ float4 sbL[PRE_NMS_N];      // 96000 B (fallback staging only)
    __shared__ u64 S[S_WORDS * S_ROWS];    // 32768 B
    __shared__ u64 kmaskLDS[NWORDS];
    __shared__ u32 kbaseLDS[NWORDS];
    __shared__ u32 lastflag;
    int lane = threadIdx.x;

    // ---- eager: rows {bid, bid+256}, words row>>6 .. 7 ----
#pragma unroll
    for (int t = 0; t < 2; ++t) {
        int i = blockIdx.x + (t << 8);     // < 512
        float4 bi = sboxes[i];             // broadcast read
        for (int w = i >> 6; w < S_WORDS; ++w) {
            int j = (w << 6) + lane;       // < 512 <= 6000
            bool sup = (j > i) && iou_gt(bi, sboxes[j]);
            u64 m = __ballot(sup);
            if (lane == 0) Mmat[i * S_WORDS + w] = m;
        }
    }

    // ---- arrival: last block reduces ----
    __syncthreads();
    if (lane == 0) {
        __threadfence();
        u64 old = atomicAdd(ctrB, 1ull);
        lastflag = (old == (u64)(GRID_B - 1)) ? 1u : 0u;
    }
    __syncthreads();
    if (!lastflag) return;
    __threadfence();   // acquire: see all blocks' M rows

    // stage S word-major
    for (int idx = lane; idx < S_WORDS * S_ROWS; idx += 64) {
        int q = idx >> 3, w = idx & 7;
        S[w * S_ROWS + q] = Mmat[q * S_WORDS + w];
    }
    __syncthreads();
    u64 lanebit = 1ull << lane;
    u64 riem0 = irem[lane];
    u64 riem1 = (lane < NWORDS - 64) ? irem[64 + lane] : ~0ull;

    int kc = 0, wend = 0;
    bool sbStaged = false;
    for (int w = 0; w < NWORDS && kc < POST_NMS_N; ++w) {
        int q0 = w << 6;
        u64 avail, myrow;

        if (w < S_WORDS) {
            // transition: avail = ~(irem[w] | OR of kept prior rows' word w)
            u64 add = 0;
            for (int wp = 0; wp < w; ++wp) {
                u64 km = kmaskLDS[wp];
                if (km & lanebit) add |= S[w * S_ROWS + (wp << 6) + lane];
            }
            if (w) {
#pragma unroll
                for (int off = 32; off >= 1; off >>= 1) add |= __shfl_xor(add, off, 64);
            }
            u64 iw = readlane_u64(riem0, w);
            avail = ~(iw | add);
            u64 diag = S[w * S_ROWS + q0 + lane];
            bool ina = (avail >> lane) & 1ull;
            myrow = ina ? (diag & avail) : 0ull;
        } else {
            // exact on-the-fly fallback (only if >212 of first 512 suppressed)
            if (!sbStaged) {
                for (int r2 = lane; r2 < PRE_NMS_N; r2 += 64) sbL[r2] = sboxes[r2];
                sbStaged = true;
                __syncthreads();
            }
            int j = q0 + lane; if (j >= PRE_NMS_N) j = PRE_NMS_N - 1;
            float4 bj = sbL[j];
            bool sup = false;
            for (int wp = 0; wp < w; ++wp) {
                u64 km = kmaskLDS[wp];
                while (km) {
                    int b = __ffsll((unsigned long long)km) - 1; km &= km - 1;
                    sup = sup || iou_gt(sbL[(wp << 6) + b], bj);
                }
            }
            u64 iw = (w < 64) ? readlane_u64(riem0, w) : readlane_u64(riem1, w - 64);
            avail = ~(iw | __ballot(sup));
            int irow = q0 + lane;
            bool rowok = (irow < PRE_NMS_N) && ((avail >> lane) & 1ull);
            float4 bi2 = sbL[rowok ? irow : 0];
            u64 my = 0;
            for (int m2 = lane + 1; m2 < 64; ++m2) {
                int jj = q0 + m2;
                if (jj >= PRE_NMS_N) break;
                if (iou_gt(bi2, sbL[jj])) my |= (1ull << m2);
            }
            myrow = rowok ? (my & avail) : 0ull;
        }

        // active = sources | targets; passive bits kept wholesale
        u64 src = __ballot(myrow != 0ull);
        u64 tor = myrow;
#pragma unroll
        for (int off = 32; off >= 1; off >>= 1) tor |= __shfl_xor(tor, off, 64);
        u64 active = (src | tor) & avail;

        u64 rm = 0;
        while (active) {
            int b = __ffsll((unsigned long long)active) - 1;
            active &= active - 1;
            if (!((rm >> b) & 1ull)) rm |= readlane_u64(myrow, b);
        }
        u64 keptw = avail & ~rm;

        if (lane == 0) { kmaskLDS[w] = keptw; kbaseLDS[w] = (u32)kc; }
        kc += __popcll(keptw);
        wend = w + 1;
    }

    // output: first min(kc,300) kept, zero-pad tail
    int nout = kc < POST_NMS_N ? kc : POST_NMS_N;
    for (int r2 = lane; r2 < POST_NMS_N; r2 += 64) {
        float4 v = make_float4(0.0f, 0.0f, 0.0f, 0.0f);
        if (r2 < nout) {
            int w = 0;
            while (w + 1 < wend && (int)kbaseLDS[w + 1] <= r2) ++w;
            int n = r2 - (int)kbaseLDS[w];
            int idx = (w << 6) + nth_set_bit(kmaskLDS[w], n);
            v = sboxes[idx];
        }
        ((float4*)out)[r2] = v;
    }
}

extern "C" void kernel_launch(void* const* d_in, const int* in_sizes, int n_in,
                              void* d_out, int out_size, void* d_ws, size_t ws_size,
                              hipStream_t stream) {
    const float4* anchors = (const float4*)d_in[0];
    const float*  cls     = (const float*)d_in[1];
    const float4* reg     = (const float4*)d_in[2];
    const int*    img_w   = (const int*)d_in[3];
    const int*    img_h   = (const int*)d_in[4];

    char* ws = (char*)d_ws;
    float4* bbox   = (float4*)(ws + OFF_BBOX);
    u64*    keys   = (u64*)   (ws + OFF_KEYS);
    float4* sboxes = (float4*)(ws + OFF_SBOX);
    u64*    irem   = (u64*)   (ws + OFF_IREM);
    u32*    actr   = (u32*)   (ws + OFF_CTR);
    u64*    ctrA   = (u64*)   (ws + OFF_CTR + 8);
    u64*    ctrB   = (u64*)   (ws + OFF_CTR + 16);
    u64*    gkraw  = (u64*)   (ws + OFF_GKRAW);
    u64*    Mmat   = (u64*)   (ws + OFF_M);

    hipMemsetAsync(ws + OFF_CTR, 0, 64, stream);   // zero append + arrival counters

    k_front<<<dim3(GRID_A), dim3(1024), 0, stream>>>(
        anchors, cls, reg, img_w, img_h, bbox, keys, gkraw, sboxes, irem, actr, ctrA);

    k_back<<<dim3(GRID_B), dim3(64), 0, stream>>>(
        sboxes, irem, Mmat, ctrB, (float*)d_out);
}

// Round 10
// 63.998 us; speedup vs baseline: 2.2151x; 1.0820x over previous
//
#include <hip/hip_runtime.h>
#include <stdint.h>

typedef unsigned long long u64;
typedef unsigned int u32;

#define N_ANCH     36864
#define PRE_NMS_N  6000
#define POST_NMS_N 300
#define NBINS_F    8192     // fallback full bin count
#define NBINS_H    2048     // happy-path scan width
#define PF_BIN     1536     // pre-filter: append keys with bin < 1536 (score >= 0.8125)
#define SEG_CAP    448      // per-block append segment (mean 192, sigma 12.5 -> 20 sigma)
#define GKH_CAP    8192
#define NWORDS     94       // ceil(6000/64)
#define S_WORDS    8        // staged words (candidates 0..511)
#define S_ROWS     512
#define GRID_A     36       // 36 x 1024 == N_ANCH
#define GRID_B     256      // rows {b, b+256} per block

// ---- workspace layout (bytes) ----
#define OFF_BBOX   0            // float4 bbox[36864]       589824
#define OFF_KEYS   589824       // u64 keys[36864]          294912 (fallback only)
#define OFF_SBOX   884736       // float4 sboxes[6000]       96000
#define OFF_IREM   980736       // u64 irem[94]                752
#define OFF_CTR    981488       // ctrA u64, ctrB u64, bcnt u32[36]  (160 B)
#define OFF_GKRAW  981648       // u64 gkraw[36*448]        129024
#define OFF_M      1110672      // u64 M[512*8]              32768
#define WS_FULL    (OFF_M + (size_t)S_ROWS * S_WORDS * 8)

// Value-uniform monotone bin: higher score -> lower bin.
__device__ __forceinline__ u32 score_bin(float s) {
    float v = fminf(fmaxf(s, 0.0f), 1.0f);
    u32 q = (u32)(v * 8192.0f);
    if (q > 8191u) q = 8191u;
    return 8191u - q;
}

// key = bin(16) | sortable_score(32) | idx(16); ascending u64 ==
// (score desc, idx asc) exactly.
__device__ __forceinline__ u64 make_key(float s, u32 bin, u32 idx) {
    u32 u = __float_as_uint(s);
    u32 sortable = u ^ ((u >> 31) ? 0xFFFFFFFFu : 0x80000000u);
    u32 hi = ~sortable;
    return ((u64)bin << 48) | ((u64)hi << 16) | (u64)idx;
}

__device__ __forceinline__ u64 readlane_u64(u64 v, int l) {
    u32 lo = __builtin_amdgcn_readlane((u32)(v & 0xFFFFFFFFull), l);
    u32 hi = __builtin_amdgcn_readlane((u32)(v >> 32), l);
    return ((u64)hi << 32) | (u64)lo;
}

__device__ __forceinline__ int nth_set_bit(u64 m, int n) {
    int pos = 0;
    u32 c = __popc((u32)m);
    if ((u32)n >= c) { n -= c; pos = 32; m >>= 32; }
    u32 x = (u32)m;
    c = __popc(x & 0xFFFFu);
    if ((u32)n >= c) { n -= c; pos += 16; x >>= 16; }
    c = __popc(x & 0xFFu);
    if ((u32)n >= c) { n -= c; pos += 8; x >>= 8; }
    c = __popc(x & 0xFu);
    if ((u32)n >= c) { n -= c; pos += 4; x >>= 4; }
    c = __popc(x & 0x3u);
    if ((u32)n >= c) { n -= c; pos += 2; x >>= 2; }
    c = x & 1u;
    if ((u32)n >= c) { pos += 1; }
    return pos;
}

// EXACT reference IoU decision (identical expression tree to all prior rounds)
__device__ __forceinline__ bool iou_gt(float4 a, float4 b) {
    float aa = (a.z - a.x) * (a.w - a.y);
    float ab = (b.z - b.x) * (b.w - b.y);
    float xx1 = fmaxf(a.x, b.x), yy1 = fmaxf(a.y, b.y);
    float xx2 = fminf(a.z, b.z), yy2 = fminf(a.w, b.w);
    float inter = fmaxf(xx2 - xx1, 0.0f) * fmaxf(yy2 - yy1, 0.0f);
    float iou = inter / (aa + ab - inter + 1e-9f);
    return iou > 0.7f;
}

// ===== K_FRONT: decode + segmented prefilter append (all blocks);
//       last-arriving block: selection chain in LDS -> sboxes + irem =====
__global__ __launch_bounds__(1024) void k_front(const float4* __restrict__ anchors,
                                                const float* __restrict__ cls,
                                                const float4* __restrict__ reg,
                                                const int* __restrict__ img_w,
                                                const int* __restrict__ img_h,
                                                float4* __restrict__ bbox,
                                                u64* __restrict__ keys,
                                                u64* __restrict__ gkraw,
                                                u32* __restrict__ bcnt,
                                                float4* __restrict__ sboxes,
                                                u64* __restrict__ irem,
                                                u64* __restrict__ ctrA) {
    __shared__ u32 histoffs[NBINS_H + 1];  // happy hist -> offsets
    __shared__ u32 cntH[NBINS_H];
    __shared__ u32 wsum[16];
    __shared__ u64 gkB[GKH_CAP];           // 64 KiB
    __shared__ u32 psum[1024];             // fallback scan
    __shared__ u32 histF[NBINS_F];         // fallback
    __shared__ u32 cntF[NBINS_F];          // fallback
    __shared__ u64 iremL[NWORDS];
    __shared__ u32 blkCnt, mB, mM, lastflag, offs_top;

    int tid = threadIdx.x, lane = tid & 63, wave = tid >> 6;
    int gi = blockIdx.x * 1024 + tid;      // exact: 36*1024 == N_ANCH

    if (tid == 0) blkCnt = 0u;
    __syncthreads();

    // ---- decode + clip + valid + key (EXACT reference arithmetic) ----
    {
        float4 a = anchors[gi];
        float4 r = reg[gi];
        float w  = a.z - a.x, h = a.w - a.y;
        float cx = a.x + 0.5f * w, cy = a.y + 0.5f * h;
        float pcx = r.x * w + cx, pcy = r.y * h + cy;
        float pw = expf(r.z) * w,  ph = expf(r.w) * h;
        float b0 = pcx - 0.5f * pw, b1 = pcy - 0.5f * ph;
        float b2 = pcx + 0.5f * pw, b3 = pcy + 0.5f * ph;

        float fh = (float)img_h[0], fw = (float)img_w[0];
        b0 = fminf(fmaxf(b0, 0.0f), fh);
        b2 = fminf(fmaxf(b2, 0.0f), fh);
        b1 = fminf(fmaxf(b1, 0.0f), fw);
        b3 = fminf(fmaxf(b3, 0.0f), fw);

        bool valid = (b2 - b0 >= 16.0f) && (b3 - b1 >= 16.0f);
        float score = valid ? cls[gi] : -1e9f;

        bbox[gi] = make_float4(b0, b1, b2, b3);
        u32 bin = score_bin(score);
        u64 key = make_key(score, bin, (u32)gi);
        keys[gi] = key;

        // wave-aggregated append into this block's private segment
        bool qf = bin < PF_BIN;
        u64 ball = __ballot(qf);
        u32 n = (u32)__popcll(ball);
        u32 wbase = 0;
        if (lane == 0 && n) wbase = atomicAdd(&blkCnt, n);
        wbase = (u32)__shfl((int)wbase, 0, 64);
        if (qf) {
            u32 pos = wbase + (u32)__popcll(ball & ((1ull << lane) - 1ull));
            if (pos < SEG_CAP) gkraw[(size_t)blockIdx.x * SEG_CAP + pos] = key;
        }
    }

    // ---- arrival (monotone modulo counter: poison-proof, no reset) ----
    __syncthreads();
    if (tid == 0) {
        bcnt[blockIdx.x] = blkCnt;
        __threadfence();
        u64 old = atomicAdd(ctrA, 1ull);
        lastflag = ((old % (u64)GRID_A) == (u64)(GRID_A - 1)) ? 1u : 0u;
    }
    __syncthreads();
    if (!lastflag) return;
    __threadfence();   // acquire: see all blocks' bbox/keys/gkraw/bcnt

    if (tid < NWORDS) iremL[tid] = ~0ull;

    // ---- gather segment counts (uniform loop, scalarizes) ----
    u32 count = 0; bool ovf = false;
    for (int b = 0; b < GRID_A; ++b) {
        u32 c = bcnt[b];
        count += c;
        ovf = ovf || (c > (u32)SEG_CAP);
    }
    bool happy = (count >= (u32)PRE_NMS_N) && !ovf;

    if (happy) {
        // top-6000 subset proof: every non-appended key has bin >= PF_BIN >
        // any appended bin, and count >= 6000 appended keys exist.
        for (int b = tid; b < NBINS_H; b += 1024) { histoffs[b] = 0u; cntH[b] = 0u; }
        __syncthreads();
        for (int i = tid; i < GRID_A * SEG_CAP; i += 1024) {
            int b = i / SEG_CAP, o = i - b * SEG_CAP;
            if (o < (int)bcnt[b])
                atomicAdd(&histoffs[(u32)(gkraw[i] >> 48)], 1u);
        }
        __syncthreads();

        // 2-barrier block scan: per-thread s over bins {2t,2t+1}, shfl wave
        // scan, 16-partial serial scan.
        u32 l0 = histoffs[2 * tid], l1 = histoffs[2 * tid + 1];
        u32 s = l0 + l1;
        u32 incv = s;
#pragma unroll
        for (int off = 1; off < 64; off <<= 1) {
            u32 v = (u32)__shfl_up((int)incv, off, 64);
            if (lane >= off) incv += v;
        }
        if (lane == 63) wsum[wave] = incv;
        __syncthreads();
        if (tid == 0) {
            u32 run = 0;
#pragma unroll
            for (int k2 = 0; k2 < 16; ++k2) { u32 t2 = wsum[k2]; wsum[k2] = run; run += t2; }
        }
        __syncthreads();
        u32 incl = wsum[wave] + incv;
        u32 excl = incl - s;
        histoffs[2 * tid] = excl;
        histoffs[2 * tid + 1] = excl + l0;
        if (tid == 1023) histoffs[NBINS_H] = incl;
        if (excl < (u32)PRE_NMS_N && incl >= (u32)PRE_NMS_N) {
            if (excl + l0 >= (u32)PRE_NMS_N) { mB = 2 * tid;     mM = excl + l0; }
            else                             { mB = 2 * tid + 1; mM = incl; }
        }
        __syncthreads();

        u32 B = mB;
        for (int i = tid; i < GRID_A * SEG_CAP; i += 1024) {
            int b = i / SEG_CAP, o = i - b * SEG_CAP;
            if (o < (int)bcnt[b]) {
                u64 k = gkraw[i];
                u32 bn = (u32)(k >> 48);
                if (bn <= B) {
                    u32 p = histoffs[bn] + atomicAdd(&cntH[bn], 1u);
                    if (p < (u32)GKH_CAP) gkB[p] = k;
                }
            }
        }
        __syncthreads();
        u32 Mtot = mM > (u32)GKH_CAP ? (u32)GKH_CAP : mM;
        for (int i = tid; i < (int)Mtot; i += 1024) {
            u64 k = gkB[i];
            u32 bn = (u32)(k >> 48);
            u32 st = histoffs[bn], en = histoffs[bn + 1];
            if (en > (u32)GKH_CAP) en = (u32)GKH_CAP;
            u32 rr = st;
            for (u32 t = st; t < en; ++t) rr += (gkB[t] < k) ? 1u : 0u;
            if (rr < (u32)PRE_NMS_N) {
                u32 idx = (u32)(k & 0xFFFFu);
                sboxes[rr] = bbox[idx];
                // appended => bin<1536 => score>=0.8125 => valid
                atomicAnd(&iremL[rr >> 6], ~(1ull << (rr & 63)));
            }
        }
    } else {
        // ---- exact fallback: full 8192-bin path over all keys ----
        for (int b = tid; b < NBINS_F; b += 1024) { histF[b] = 0u; cntF[b] = 0u; }
        __syncthreads();
        for (int i = tid; i < N_ANCH; i += 1024)
            atomicAdd(&histF[(u32)(keys[i] >> 48)], 1u);
        __syncthreads();
        u32 loc[8]; u32 s = 0;
        int base8 = tid * 8;
#pragma unroll
        for (int t = 0; t < 8; ++t) { loc[t] = histF[base8 + t]; s += loc[t]; }
        psum[tid] = s;
        __syncthreads();
        for (int off = 1; off < 1024; off <<= 1) {
            u32 v = (tid >= off) ? psum[tid - off] : 0u;
            __syncthreads();
            psum[tid] += v;
            __syncthreads();
        }
        u32 incl = psum[tid], excl = incl - s;
        u32 run = excl;
#pragma unroll
        for (int t = 0; t < 8; ++t) { histF[base8 + t] = run; run += loc[t]; }
        if (tid == 1023) offs_top = incl;
        if (excl < (u32)PRE_NMS_N && incl >= (u32)PRE_NMS_N) {
            u32 c = excl;
#pragma unroll
            for (int t = 0; t < 8; ++t) {
                if (c + loc[t] >= (u32)PRE_NMS_N) { mB = (u32)(base8 + t); mM = c + loc[t]; break; }
                c += loc[t];
            }
        }
        __syncthreads();
        u32 B = mB;
        for (int i = tid; i < N_ANCH; i += 1024) {
            u64 k = keys[i];
            u32 bn = (u32)(k >> 48);
            if (bn <= B) {
                u32 p = histF[bn] + atomicAdd(&cntF[bn], 1u);
                if (p < (u32)GKH_CAP) gkB[p] = k;
            }
        }
        __syncthreads();
        u32 Mtot = mM > (u32)GKH_CAP ? (u32)GKH_CAP : mM;
        for (int i = tid; i < (int)Mtot; i += 1024) {
            u64 k = gkB[i];
            u32 bn = (u32)(k >> 48);
            u32 st = histF[bn];
            u32 en = (bn + 1 < (u32)NBINS_F) ? histF[bn + 1] : offs_top;
            if (en > (u32)GKH_CAP) en = (u32)GKH_CAP;
            u32 rr = st;
            for (u32 t = st; t < en; ++t) rr += (gkB[t] < k) ? 1u : 0u;
            if (rr < (u32)PRE_NMS_N) {
                u32 idx = (u32)(k & 0xFFFFu);
                float4 b = bbox[idx];
                sboxes[rr] = b;
                bool valid = (b.z - b.x >= 16.0f) && (b.w - b.y >= 16.0f);
                if (valid) atomicAnd(&iremL[rr >> 6], ~(1ull << (rr & 63)));
            }
        }
    }
    __syncthreads();
    if (tid < NWORDS) irem[tid] = iremL[tid];
}

// ===== K_BACK: eager IoU rows<512 x words<8 (all blocks); last block reduces =====
__global__ __launch_bounds__(64) void k_back(const float4* __restrict__ sboxes,
                                             const u64* __restrict__ irem,
                                             u64* __restrict__ Mmat,
                                             u64* __restrict__ ctrB,
                                             float* __restrict__ out) {
    __shared__ float4 sbL[PRE_NMS_N];      // fallback staging only
    __shared__ u64 S[S_WORDS * S_ROWS];    // 32768 B
    __shared__ u64 kmaskLDS[NWORDS];
    __shared__ u32 kbaseLDS[NWORDS];
    __shared__ u32 lastflag;
    int lane = threadIdx.x;

    // ---- eager: rows {bid, bid+256}, words row>>6 .. 7 ----
#pragma unroll
    for (int t = 0; t < 2; ++t) {
        int i = blockIdx.x + (t << 8);     // < 512
        float4 bi = sboxes[i];
        for (int w = i >> 6; w < S_WORDS; ++w) {
            int j = (w << 6) + lane;       // < 512
            bool sup = (j > i) && iou_gt(bi, sboxes[j]);
            u64 m = __ballot(sup);
            if (lane == 0) Mmat[i * S_WORDS + w] = m;
        }
    }

    // ---- arrival (monotone modulo counter) ----
    __syncthreads();
    if (lane == 0) {
        __threadfence();
        u64 old = atomicAdd(ctrB, 1ull);
        lastflag = ((old % (u64)GRID_B) == (u64)(GRID_B - 1)) ? 1u : 0u;
    }
    __syncthreads();
    if (!lastflag) return;
    __threadfence();   // acquire

    for (int idx = lane; idx < S_WORDS * S_ROWS; idx += 64) {
        int q = idx >> 3, w = idx & 7;
        S[w * S_ROWS + q] = Mmat[q * S_WORDS + w];
    }
    __syncthreads();
    u64 lanebit = 1ull << lane;
    u64 riem0 = irem[lane];
    u64 riem1 = (lane < NWORDS - 64) ? irem[64 + lane] : ~0ull;

    int kc = 0, wend = 0;
    bool sbStaged = false;
    for (int w = 0; w < NWORDS && kc < POST_NMS_N; ++w) {
        int q0 = w << 6;
        u64 avail, myrow;

        if (w < S_WORDS) {
            u64 add = 0;
            for (int wp = 0; wp < w; ++wp) {
                u64 km = kmaskLDS[wp];
                if (km & lanebit) add |= S[w * S_ROWS + (wp << 6) + lane];
            }
            if (w) {
#pragma unroll
                for (int off = 32; off >= 1; off >>= 1) add |= __shfl_xor(add, off, 64);
            }
            u64 iw = readlane_u64(riem0, w);
            avail = ~(iw | add);
            u64 diag = S[w * S_ROWS + q0 + lane];
            bool ina = (avail >> lane) & 1ull;
            myrow = ina ? (diag & avail) : 0ull;
        } else {
            // exact on-the-fly fallback (only if >212 of first 512 suppressed)
            if (!sbStaged) {
                for (int r2 = lane; r2 < PRE_NMS_N; r2 += 64) sbL[r2] = sboxes[r2];
                sbStaged = true;
                __syncthreads();
            }
            int j = q0 + lane; if (j >= PRE_NMS_N) j = PRE_NMS_N - 1;
            float4 bj = sbL[j];
            bool sup = false;
            for (int wp = 0; wp < w; ++wp) {
                u64 km = kmaskLDS[wp];
                while (km) {
                    int b = __ffsll((unsigned long long)km) - 1; km &= km - 1;
                    sup = sup || iou_gt(sbL[(wp << 6) + b], bj);
                }
            }
            u64 iw = (w < 64) ? readlane_u64(riem0, w) : readlane_u64(riem1, w - 64);
            avail = ~(iw | __ballot(sup));
            int irow = q0 + lane;
            bool rowok = (irow < PRE_NMS_N) && ((avail >> lane) & 1ull);
            float4 bi2 = sbL[rowok ? irow : 0];
            u64 my = 0;
            for (int m2 = lane + 1; m2 < 64; ++m2) {
                int jj = q0 + m2;
                if (jj >= PRE_NMS_N) break;
                if (iou_gt(bi2, sbL[jj])) my |= (1ull << m2);
            }
            myrow = rowok ? (my & avail) : 0ull;
        }

        u64 src = __ballot(myrow != 0ull);
        u64 tor = myrow;
#pragma unroll
        for (int off = 32; off >= 1; off >>= 1) tor |= __shfl_xor(tor, off, 64);
        u64 active = (src | tor) & avail;

        u64 rm = 0;
        while (active) {
            int b = __ffsll((unsigned long long)active) - 1;
            active &= active - 1;
            if (!((rm >> b) & 1ull)) rm |= readlane_u64(myrow, b);
        }
        u64 keptw = avail & ~rm;

        if (lane == 0) { kmaskLDS[w] = keptw; kbaseLDS[w] = (u32)kc; }
        kc += __popcll(keptw);
        wend = w + 1;
    }

    int nout = kc < POST_NMS_N ? kc : POST_NMS_N;
    for (int r2 = lane; r2 < POST_NMS_N; r2 += 64) {
        float4 v = make_float4(0.0f, 0.0f, 0.0f, 0.0f);
        if (r2 < nout) {
            int w = 0;
            while (w + 1 < wend && (int)kbaseLDS[w + 1] <= r2) ++w;
            int n = r2 - (int)kbaseLDS[w];
            int idx = (w << 6) + nth_set_bit(kmaskLDS[w], n);
            v = sboxes[idx];
        }
        ((float4*)out)[r2] = v;
    }
}

extern "C" void kernel_launch(void* const* d_in, const int* in_sizes, int n_in,
                              void* d_out, int out_size, void* d_ws, size_t ws_size,
                              hipStream_t stream) {
    const float4* anchors = (const float4*)d_in[0];
    const float*  cls     = (const float*)d_in[1];
    const float4* reg     = (const float4*)d_in[2];
    const int*    img_w   = (const int*)d_in[3];
    const int*    img_h   = (const int*)d_in[4];

    char* ws = (char*)d_ws;
    float4* bbox   = (float4*)(ws + OFF_BBOX);
    u64*    keys   = (u64*)   (ws + OFF_KEYS);
    float4* sboxes = (float4*)(ws + OFF_SBOX);
    u64*    irem   = (u64*)   (ws + OFF_IREM);
    u64*    ctrA   = (u64*)   (ws + OFF_CTR);
    u64*    ctrB   = (u64*)   (ws + OFF_CTR + 8);
    u32*    bcnt   = (u32*)   (ws + OFF_CTR + 16);
    u64*    gkraw  = (u64*)   (ws + OFF_GKRAW);
    u64*    Mmat   = (u64*)   (ws + OFF_M);

    k_front<<<dim3(GRID_A), dim3(1024), 0, stream>>>(
        anchors, cls, reg, img_w, img_h, bbox, keys, gkraw, bcnt, sboxes, irem, ctrA);

    k_back<<<dim3(GRID_B), dim3(64), 0, stream>>>(
        sboxes, irem, Mmat, ctrB, (float*)d_out);
}